// Round 8
// baseline (1158.532 us; speedup 1.0000x reference)
//
#include <hip/hip_runtime.h>

#pragma clang fp contract(off)

typedef unsigned long long u64;
typedef unsigned int u32;

#define ALPHA  0.9f
#define RHO    0.985f
#define BETA_A 1.8f
#define TH     1.0f
#define CAP    (1 << 24)

// ---------------------------------------------------------------------------
// Generic 32x32 tiled transpose: src[R][C] -> dst[C][R]
// ---------------------------------------------------------------------------
__global__ __launch_bounds__(256) void transpose_k(const float* __restrict__ src,
                                                   float* __restrict__ dst,
                                                   int R, int C) {
    __shared__ float tile[32][33];
    const int c0 = blockIdx.x * 32;
    const int r0 = blockIdx.y * 32;
    const int tx = threadIdx.x, ty = threadIdx.y;
#pragma unroll
    for (int i = 0; i < 4; ++i)
        tile[ty + i * 8][tx] = src[(r0 + ty + i * 8) * C + c0 + tx];
    __syncthreads();
#pragma unroll
    for (int i = 0; i < 4; ++i)
        dst[(c0 + ty + i * 8) * R + r0 + tx] = tile[tx][ty + i * 8];
}

// ---------------------------------------------------------------------------
// Input projection: out[r][n] = sum_k inp[r][k] * Wt[k][n] + bias[n]
// ---------------------------------------------------------------------------
__global__ __launch_bounds__(256) void ip_gemm(const float* __restrict__ inp,
                                               const float* __restrict__ Wt,
                                               const float* __restrict__ bias,
                                               float* __restrict__ out) {
    __shared__ __align__(16) float s_in[512 * 20];
    const int tid   = threadIdx.x;
    const int chunk = blockIdx.x;
    const int rbase = blockIdx.y * 16;

    for (int idx = tid; idx < 16 * 512; idx += 256) {
        const int r = idx >> 9, k = idx & 511;
        s_in[k * 20 + r] = inp[(rbase + r) * 512 + k];
    }
    __syncthreads();

    const int n = chunk * 256 + tid;
    float acc[16];
#pragma unroll
    for (int r = 0; r < 16; ++r) acc[r] = 0.f;

    for (int k = 0; k < 512; ++k) {
        const float w = Wt[k * 1024 + n];
        const float4* p = (const float4*)(s_in + k * 20);
        const float4 x0 = p[0], x1 = p[1], x2 = p[2], x3 = p[3];
        acc[0]  = fmaf(x0.x, w, acc[0]);  acc[1]  = fmaf(x0.y, w, acc[1]);
        acc[2]  = fmaf(x0.z, w, acc[2]);  acc[3]  = fmaf(x0.w, w, acc[3]);
        acc[4]  = fmaf(x1.x, w, acc[4]);  acc[5]  = fmaf(x1.y, w, acc[5]);
        acc[6]  = fmaf(x1.z, w, acc[6]);  acc[7]  = fmaf(x1.w, w, acc[7]);
        acc[8]  = fmaf(x2.x, w, acc[8]);  acc[9]  = fmaf(x2.y, w, acc[9]);
        acc[10] = fmaf(x2.z, w, acc[10]); acc[11] = fmaf(x2.w, w, acc[11]);
        acc[12] = fmaf(x3.x, w, acc[12]); acc[13] = fmaf(x3.y, w, acc[13]);
        acc[14] = fmaf(x3.z, w, acc[14]); acc[15] = fmaf(x3.w, w, acc[15]);
    }
    const float bn = bias[n];
#pragma unroll
    for (int r = 0; r < 16; ++r) out[(rbase + r) * 1024 + n] = acc[r] + bn;
}

// ---------------------------------------------------------------------------
__device__ __forceinline__ u64 ld_u64(const u64* p) {
    return __hip_atomic_load(p, __ATOMIC_RELAXED, __HIP_MEMORY_SCOPE_AGENT);
}
__device__ __forceinline__ void st_u64(u64* p, u64 v) {
    __hip_atomic_store(p, v, __ATOMIC_RELAXED, __HIP_MEMORY_SCOPE_AGENT);
}

// Gather over byte-offset list segment [i0, i1), i0 % 4 == 0.
// Entries are row byte-offsets (j*4096); address = uniform base + 32-bit off.
// (Identical structure to round 7 -- summation order preserved.)
__device__ __forceinline__ float gatherseg(const char* __restrict__ Wb,
                                           const int* __restrict__ list,
                                           int i0, int i1, int colB) {
    float a0 = 0.f, a1 = 0.f, a2 = 0.f, a3 = 0.f;
    int i = i0;
    for (; i + 4 <= i1; i += 4) {
        const int4 j = *(const int4*)(list + i);
        a0 += *(const float*)(Wb + (u32)(j.x + colB));
        a1 += *(const float*)(Wb + (u32)(j.y + colB));
        a2 += *(const float*)(Wb + (u32)(j.z + colB));
        a3 += *(const float*)(Wb + (u32)(j.w + colB));
    }
    for (; i < i1; ++i) a0 += *(const float*)(Wb + (u32)(list[i] + colB));
    return (a0 + a1) + (a2 + a3);
}

// index-based gather for out_gemm
__device__ __forceinline__ float gather_idx(const float* __restrict__ W,
                                            const int* __restrict__ list, int cnt, int col) {
    float a0 = 0.f, a1 = 0.f, a2 = 0.f, a3 = 0.f;
    int i = 0;
    for (; i + 4 <= cnt; i += 4) {
        const int4 j = *(const int4*)(list + i);
        a0 += W[j.x * 256 + col];
        a1 += W[j.y * 256 + col];
        a2 += W[j.z * 256 + col];
        a3 += W[j.w * 256 + col];
    }
    for (; i < cnt; ++i) a0 += W[list[i] * 256 + col];
    return (a0 + a1) + (a2 + a3);
}

// ---------------------------------------------------------------------------
// Per-batch producer-consumer kernel: 512 blocks x 320 threads (2 blocks/CU
// -> two independent barrier domains per CU; one block's poll/barrier stalls
// are hidden by the other's gathers).
// bid = g*8+x; slice s = x>>1 (cols [s*256,s*256+256), XCD-pinned via bid%8);
// batch b = g*2+(x&1). Waves 0-3 compute (64 cols each); wave 4 = comm wave
// (polls exchange-1, builds listP; B1; polls exchange-2, builds listS[par]; B2).
// Exchange lines per (batch,par,ty): 4 slices x 8 words of (e<<32)|bits32.
// Pipeline (same as round 7): FILL-1 = first half of C(e-1); FILL-2 = rest of
// C(e-1) + v_post(e-1) finish; s_post emitted when e%3==1 (ph=e-1 has k==2).
// ---------------------------------------------------------------------------
__global__ __launch_bounds__(320) void rsnn_pc2(
    const float* __restrict__ Wt_pre,   // [1536][1024]
    const float* __restrict__ Wt_ad,    // [1024][1024]
    const float* __restrict__ Wt_post,  // [1536][1024]
    const float* __restrict__ IP_pre,   // [4096][1024]
    const float* __restrict__ IP_post,  // [4096][1024]
    const float* __restrict__ b_ad_p,   // [1024]
    u64* __restrict__ lines,            // [128][2 par][2 ty][32]
    u64* __restrict__ spkO,             // [4096][16]
    float* __restrict__ out)
{
    const int tid  = threadIdx.x;
    const int bid  = blockIdx.x;
    const int x    = bid & 7;
    const int g    = bid >> 3;
    const int s    = x >> 1;
    const int b    = g * 2 + (x & 1);
    const int wid  = tid >> 6;
    const int lane = tid & 63;

    __shared__ __align__(16) int listP[1024];
    __shared__ __align__(16) int listS[2][1024];
    __shared__ int cntP_ls, cntS_ls[2];

    const char* WadB    = (const char*)Wt_ad;
    const char* WpreAB  = (const char*)(Wt_pre  + 512 * 1024);
    const char* WpostAB = (const char*)(Wt_post + 512 * 1024);

    if (tid == 0) { cntS_ls[0] = 0; cntS_ls[1] = 0; cntP_ls = 0; }
    __syncthreads();   // (comm wave also passes here: pre-loop init barrier)

    if (wid < 4) {
        // ============================ compute ============================
        const int q    = wid;              // col quarter
        const int col  = s * 256 + tid;    // tid in [0,256)
        const int colB = col * 4;

        float v_pre = 0.f, v_a = 0.f, ba = 0.f, v_post = 0.f, accA = 0.f;
        bool  sa = false;
        const float bad = b_ad_p[col];
        float g1 = 0.f;
        int halfPrev = 0, cntPrev = 0, parPrev = 0;

        for (int e = 1; e <= 96; ++e) {
            const int par = e & 1;
            const int t   = (e - 1) / 3;
            const float ipre = IP_pre[(t * 128 + b) * 1024 + col];
            u64* ln0 = lines + ((b * 2 + par) * 2 + 0) * 32;
            u64* ln1 = lines + ((b * 2 + par) * 2 + 1) * 32;

            // ---- A: v_pre update, immediate per-wave publish ----
            v_pre = ALPHA * v_pre + ipre + accA;
            float d = v_pre - TH;
            const bool sp = d > 0.f;
            if (sp) v_pre = d;
            {
                const u64 m = __ballot(sp);
                if (lane == 0) {
                    const u64 eh = ((u64)e) << 32;
                    st_u64(&ln0[s * 8 + 2 * q],     eh | (m & 0xffffffffull));
                    st_u64(&ln0[s * 8 + 2 * q + 1], eh | (m >> 32));
                }
            }
            // ---- FILL-1: first half of C(e-1) gather ----
            if (e >= 2)
                g1 = gatherseg(WpostAB, listS[parPrev], 0, halfPrev, colB);
            __syncthreads();                                      // B1

            // ---- B: gather full s_pre list, v_a update, publish s_a ----
            const int cp = cntP_ls;
            const float accB = gatherseg(WadB, listP, 0, cp, colB);
            v_a = ALPHA * v_a + accB + bad;
            const float th = TH + BETA_A * ba;
            d = v_a - th;
            sa = d > 0.f;
            if (sa) v_a = d;
            ba = RHO * ba + (sa ? 1.f : 0.f);
            {
                const u64 m = __ballot(sa);
                if (lane == 0) {
                    const u64 eh = ((u64)e) << 32;
                    st_u64(&ln1[s * 8 + 2 * q],     eh | (m & 0xffffffffull));
                    st_u64(&ln1[s * 8 + 2 * q + 1], eh | (m >> 32));
                }
            }
            // ---- FILL-2: rest of C(e-1), finish v_post(e-1) ----
            if (e >= 2) {
                const float g2 = gatherseg(WpostAB, listS[parPrev],
                                           halfPrev, cntPrev, colB);
                const int tp = (e - 2) / 3;
                const float ipost = IP_post[(tp * 128 + b) * 1024 + col];
                v_post = ALPHA * v_post + ipost + (g1 + g2);
                float dd = v_post - TH;
                const bool spost = dd > 0.f;
                if (spost) v_post = dd;
                if (e % 3 == 1) {   // ph=e-1 has k==2
                    const u64 m = __ballot(spost);
                    if (lane == 0)
                        st_u64(&spkO[(tp * 128 + b) * 16 + s * 4 + q], m);
                }
            }
            if (e == 96)
                out[32 * 128 * 256 + b * 1024 + col] = sa ? 1.f : 0.f;
            __syncthreads();                                      // B2

            // ---- next-A gather from fresh listS ----
            const int cs = cntS_ls[par];
            halfPrev = (cs >> 1) & ~3;
            cntPrev  = cs;
            parPrev  = par;
            if (e < 96)
                accA = gatherseg(WpreAB, listS[par], 0, cs, colB);
        }
        // ---- epilogue: v_post(96) (par(96) == 0) ----
        {
            const float ga = gatherseg(WpostAB, listS[0], 0, halfPrev, colB);
            const float gb = gatherseg(WpostAB, listS[0], halfPrev, cntPrev, colB);
            const float ipost = IP_post[(31 * 128 + b) * 1024 + col];
            v_post = ALPHA * v_post + ipost + (ga + gb);
            const float dd = v_post - TH;
            const u64 m = __ballot(dd > 0.f);
            if (lane == 0)
                st_u64(&spkO[(31 * 128 + b) * 16 + s * 4 + q], m);
        }
    } else {
        // ====================== comm wave (wid == 4) ======================
        const int sl = lane >> 3, h = lane & 7;     // lanes 0-31 active
        const bool act = lane < 32;
        const int jbase = (sl * 256 + h * 32) << 12;
        for (int e = 1; e <= 96; ++e) {
            const int par = e & 1;
            const u64* ln0 = lines + ((b * 2 + par) * 2 + 0) * 32;
            const u64* ln1 = lines + ((b * 2 + par) * 2 + 1) * 32;

            // ---- exchange-1 -> listP ----
            u32 bits = 0;
            if (act) {
                u64 w; int gd = 0;
                do { w = ld_u64(&ln0[sl * 8 + h]); }
                while ((w >> 32) != (u64)e && ++gd < CAP);
                bits = (u32)w;
            }
            {
                const int pc = __popc(bits);
                int incl = pc;
#pragma unroll
                for (int dlt = 1; dlt < 32; dlt <<= 1) {
                    const int v = __shfl_up(incl, dlt, 64);
                    if (lane >= dlt && lane < 32) incl += v;
                }
                int base = incl - pc;
                u32 m = bits;
                while (m) {
                    const int bt = __builtin_ctz(m);
                    m &= m - 1;
                    listP[base++] = jbase + (bt << 12);
                }
                if (lane == 31) cntP_ls = incl;
            }
            __syncthreads();                                      // B1

            // ---- exchange-2 -> listS[par] ----
            bits = 0;
            if (act) {
                u64 w; int gd = 0;
                do { w = ld_u64(&ln1[sl * 8 + h]); }
                while ((w >> 32) != (u64)e && ++gd < CAP);
                bits = (u32)w;
            }
            {
                const int pc = __popc(bits);
                int incl = pc;
#pragma unroll
                for (int dlt = 1; dlt < 32; dlt <<= 1) {
                    const int v = __shfl_up(incl, dlt, 64);
                    if (lane >= dlt && lane < 32) incl += v;
                }
                int base = incl - pc;
                u32 m = bits;
                while (m) {
                    const int bt = __builtin_ctz(m);
                    m &= m - 1;
                    listS[par][base++] = jbase + (bt << 12);
                }
                if (lane == 31) cntS_ls[par] = incl;
            }
            __syncthreads();                                      // B2
        }
    }
}

// ---------------------------------------------------------------------------
// Final output GEMM: o[r] = s_post[r] @ W_out.T + b_out, from spkO bitmaps.
// ---------------------------------------------------------------------------
__global__ __launch_bounds__(256) void out_gemm(const float* __restrict__ Wt_out,
                                                const float* __restrict__ b_out,
                                                const u64* __restrict__ spkO,
                                                float* __restrict__ out) {
    __shared__ u64 bmp[16];
    __shared__ int pc[16];
    __shared__ __align__(16) int list[1024];
    const int r = blockIdx.x, tid = threadIdx.x;
    if (tid < 16) {
        const u64 m = ld_u64(&spkO[r * 16 + tid]);
        bmp[tid] = m;
        pc[tid]  = __popcll(m);
    }
    __syncthreads();
    int total = 0;
#pragma unroll
    for (int w = 0; w < 16; ++w) total += pc[w];
    for (int j = tid; j < 1024; j += 256) {
        const int w = j >> 6, bit = j & 63;
        const u64 m = bmp[w];
        if ((m >> bit) & 1ull) {
            int base = __popcll(m & ((1ull << bit) - 1ull));
            for (int q2 = 0; q2 < w; ++q2) base += pc[q2];
            list[base] = j;
        }
    }
    __syncthreads();
    const float acc = gather_idx(Wt_out, list, total, tid);
    out[r * 256 + tid] = acc + b_out[tid];
}

// ---------------------------------------------------------------------------
extern "C" void kernel_launch(void* const* d_in, const int* in_sizes, int n_in,
                              void* d_out, int out_size, void* d_ws, size_t ws_size,
                              hipStream_t stream) {
    (void)in_sizes; (void)n_in; (void)out_size; (void)ws_size;
    const float* inp    = (const float*)d_in[0];
    const float* W_pre  = (const float*)d_in[1];
    const float* b_pre  = (const float*)d_in[2];
    const float* W_ad   = (const float*)d_in[3];
    const float* b_ad   = (const float*)d_in[4];
    const float* W_post = (const float*)d_in[5];
    const float* b_post = (const float*)d_in[6];
    const float* W_out  = (const float*)d_in[7];
    const float* b_out  = (const float*)d_in[8];

    char* base = (char*)d_ws;
    u64*  lines = (u64*)(base + 4096);               // 128 KB exchange lines
    u64*  spkO  = (u64*)(base + 4096 + 131072);      // 512 KB
    float* ws      = (float*)(base + 1048576);
    float* Wt_pre  = ws;
    float* Wt_post = Wt_pre  + 1536 * 1024;
    float* Wt_ad   = Wt_post + 1536 * 1024;
    float* Wt_out  = Wt_ad   + 1024 * 1024;
    float* IP_pre  = Wt_out  + 1024 * 256;
    float* IP_post = IP_pre  + 4096 * 1024;

    hipMemsetAsync(base, 0, 4096 + 131072, stream);  // zero exchange lines

    transpose_k<<<dim3(48, 32), dim3(32, 8), 0, stream>>>(W_pre,  Wt_pre,  1024, 1536);
    transpose_k<<<dim3(48, 32), dim3(32, 8), 0, stream>>>(W_post, Wt_post, 1024, 1536);
    transpose_k<<<dim3(32, 32), dim3(32, 8), 0, stream>>>(W_ad,   Wt_ad,   1024, 1024);
    transpose_k<<<dim3(32, 8),  dim3(32, 8), 0, stream>>>(W_out,  Wt_out,  256,  1024);

    ip_gemm<<<dim3(4, 256), 256, 0, stream>>>(inp, Wt_pre,  b_pre,  IP_pre);
    ip_gemm<<<dim3(4, 256), 256, 0, stream>>>(inp, Wt_post, b_post, IP_post);

    rsnn_pc2<<<512, 320, 0, stream>>>(Wt_pre, Wt_ad, Wt_post,
                                      IP_pre, IP_post, b_ad,
                                      lines, spkO, (float*)d_out);

    out_gemm<<<4096, 256, 0, stream>>>(Wt_out, b_out, spkO, (float*)d_out);
}